// Round 5
// baseline (203.385 us; speedup 1.0000x reference)
//
#include <hip/hip_runtime.h>

#define N_NODES 20000
#define N_EDGES 640000
#define N_GRAPHS 64

// pool tiling
#define NCHUNK 128
#define CHUNK_SZ 157   // 128*157 = 20096 >= 20000
#define GSPLIT 8       // graph-dim split: 8 blocks of 8 graphs each
#define GSUB 8

// hist partition
#define NRANGE 16
#define NSLAB 1250         // nodes per range (16*1250 = 20000)
#define NSLICE 16
#define ESLICE 40000       // edges per slice (16*40000 = 640000)
#define SLABW 20000        // u32 words per cd slab: 1250*64 bytes / 4
#define DEGW 625           // u32 words per deg slab: 1250 u16 / 2

// ws layout (4B units), ws_size = 256 MiB (harness poison fill shows 262144 KB):
//   Cd      [8][20000][8] f32   at 0          (1,280,000) split-major
//   deg     [20000] f32         at 1,280,000
//   counts  [64] f32            at 1,300,000  (zeroed by hist_k blk0)
//   Y       [128][256] f32      at 1,300,064  (rows 0..63 zeroed by hist_k blk0)
//   part    [128][64][256] f32  at 1,332,832  (2,097,152)
//   cdpart  [256][20000] u32    at 3,429,984  (5,120,000)
//   degpart [256][625] u32      at 8,549,984  (160,000)
// end = 8,709,984 words = 34.8 MB << 256 MiB
#define CD_OFF      0
#define DEG_OFF     1280000
#define CNT_OFF     1300000
#define Y_OFF       1300064
#define PART_OFF    1332832
#define CDPART_OFF  3429984
#define DEGPART_OFF 8549984

// 256 blocks = 16 node-ranges x 16 edge-slices. 8-bit (dst,graph) hist + 16-bit
// src-degree hist in LDS; dense partial writes, zero global atomics.
__global__ __launch_bounds__(256) void hist_k(const int* __restrict__ ei,
                                              const int* __restrict__ batch,
                                              unsigned* __restrict__ cdpart,
                                              unsigned* __restrict__ degpart,
                                              float* __restrict__ Y,
                                              float* __restrict__ counts) {
    __shared__ unsigned slab[SLABW];   // 80 KB: 1250 nodes x 64 graphs, u8 counters
    __shared__ unsigned sdeg[DEGW];    // 2.5 KB: 1250 u16 counters
    const int t = threadIdx.x;
    const int range = blockIdx.x >> 4;
    const int slice = blockIdx.x & 15;

    for (int i = t; i < SLABW; i += 256) slab[i] = 0u;
    for (int i = t; i < DEGW; i += 256) sdeg[i] = 0u;
    if (blockIdx.x == 0) {             // zero atomic targets (replaces memset dispatch)
        float4* y4 = (float4*)Y;
        for (int i = t; i < 64 * 64; i += 256) y4[i] = make_float4(0.f, 0.f, 0.f, 0.f);
        if (t < N_GRAPHS) counts[t] = 0.0f;
    }
    __syncthreads();

    const int r0 = range * NSLAB;
    const int e0 = slice * ESLICE;
    for (int i = t; i < ESLICE; i += 256) {
        int s = ei[e0 + i];
        int d = ei[N_EDGES + e0 + i];
        int rd = d - r0;
        if ((unsigned)rd < (unsigned)NSLAB) {
            int g = batch[s];                         // gather only when in-range
            unsigned bi = (unsigned)(rd * 64 + g);
            atomicAdd(&slab[bi >> 2], 1u << ((bi & 3u) * 8));
        }
        int rs = s - r0;
        if ((unsigned)rs < (unsigned)NSLAB)
            atomicAdd(&sdeg[rs >> 1], 1u << ((rs & 1u) * 16));
    }
    __syncthreads();

    unsigned* outc = cdpart + (size_t)blockIdx.x * SLABW;
    for (int i = t; i < SLABW; i += 256) outc[i] = slab[i];
    unsigned* outd = degpart + (size_t)blockIdx.x * DEGW;
    for (int i = t; i < DEGW; i += 256) outd[i] = sdeg[i];
}

// merge 16 slices: unpack bytes -> Cd f32 (split-major), deg f32, counts.
__global__ __launch_bounds__(256) void cd_reduce_k(const unsigned* __restrict__ cdpart,
                                                   const unsigned* __restrict__ degpart,
                                                   const int* __restrict__ batch,
                                                   float* __restrict__ Cd,
                                                   float* __restrict__ deg,
                                                   float* __restrict__ counts) {
    __shared__ float lh[N_GRAPHS];
    const int t = threadIdx.x;
    if (t < N_GRAPHS) lh[t] = 0.0f;
    __syncthreads();

    const int ln = t >> 4;                 // 16 nodes per block
    const int gq = t & 15;                 // graph quad: graphs 4gq..4gq+3
    const int n = blockIdx.x * 16 + ln;    // 1250 blocks
    const int range = n / NSLAB;
    const int idx = n - range * NSLAB;
    const size_t base = (size_t)(range * NSLICE) * SLABW + idx * 16 + gq;
    unsigned a0 = 0, a1 = 0, a2 = 0, a3 = 0;
    for (int s = 0; s < NSLICE; ++s) {
        unsigned v = cdpart[base + (size_t)s * SLABW];   // coalesced across block
        a0 += v & 255u; a1 += (v >> 8) & 255u; a2 += (v >> 16) & 255u; a3 += v >> 24;
    }
    const int j = gq >> 1;                 // split = g>>3 = gq>>1
    float4* dst = (float4*)(Cd + ((size_t)j * N_NODES + n) * GSUB + (gq & 1) * 4);
    *dst = make_float4((float)a0, (float)a1, (float)a2, (float)a3);

    if (gq == 0) {
        const size_t db = (size_t)(range * NSLICE) * DEGW + (idx >> 1);
        const unsigned sh = (idx & 1) * 16;
        unsigned acc = 0;
        for (int s = 0; s < NSLICE; ++s) acc += (degpart[db + (size_t)s * DEGW] >> sh) & 0xFFFFu;
        float dv = (float)acc;
        deg[n] = dv;
        if (dv != 0.0f) atomicAdd(&lh[batch[n]], dv);
    }
    __syncthreads();
    if (t < N_GRAPHS && lh[t] != 0.0f) atomicAdd(&counts[t], lh[t]);
}

#define FMA8(C0, C1, XV)                                          \
    acc[0].x = fmaf(C0.x, XV.x, acc[0].x); acc[0].y = fmaf(C0.x, XV.y, acc[0].y); \
    acc[0].z = fmaf(C0.x, XV.z, acc[0].z); acc[0].w = fmaf(C0.x, XV.w, acc[0].w); \
    acc[1].x = fmaf(C0.y, XV.x, acc[1].x); acc[1].y = fmaf(C0.y, XV.y, acc[1].y); \
    acc[1].z = fmaf(C0.y, XV.z, acc[1].z); acc[1].w = fmaf(C0.y, XV.w, acc[1].w); \
    acc[2].x = fmaf(C0.z, XV.x, acc[2].x); acc[2].y = fmaf(C0.z, XV.y, acc[2].y); \
    acc[2].z = fmaf(C0.z, XV.z, acc[2].z); acc[2].w = fmaf(C0.z, XV.w, acc[2].w); \
    acc[3].x = fmaf(C0.w, XV.x, acc[3].x); acc[3].y = fmaf(C0.w, XV.y, acc[3].y); \
    acc[3].z = fmaf(C0.w, XV.z, acc[3].z); acc[3].w = fmaf(C0.w, XV.w, acc[3].w); \
    acc[4].x = fmaf(C1.x, XV.x, acc[4].x); acc[4].y = fmaf(C1.x, XV.y, acc[4].y); \
    acc[4].z = fmaf(C1.x, XV.z, acc[4].z); acc[4].w = fmaf(C1.x, XV.w, acc[4].w); \
    acc[5].x = fmaf(C1.y, XV.x, acc[5].x); acc[5].y = fmaf(C1.y, XV.y, acc[5].y); \
    acc[5].z = fmaf(C1.y, XV.z, acc[5].z); acc[5].w = fmaf(C1.y, XV.w, acc[5].w); \
    acc[6].x = fmaf(C1.z, XV.x, acc[6].x); acc[6].y = fmaf(C1.z, XV.y, acc[6].y); \
    acc[6].z = fmaf(C1.z, XV.z, acc[6].z); acc[6].w = fmaf(C1.z, XV.w, acc[6].w); \
    acc[7].x = fmaf(C1.w, XV.x, acc[7].x); acc[7].y = fmaf(C1.w, XV.y, acc[7].y); \
    acc[7].z = fmaf(C1.w, XV.z, acc[7].z); acc[7].w = fmaf(C1.w, XV.w, acc[7].w);

// pool: block = (chunk b, split j of 8 graphs). 4 waves = 4 node phases,
// x prefetched one iteration ahead, LDS float4 Cd reads, tree reduce.
__global__ __launch_bounds__(256) void pool_k(const float* __restrict__ x,
                                              const int* __restrict__ batch,
                                              const float* __restrict__ Cd,
                                              const float* __restrict__ deg,
                                              float* __restrict__ Y,
                                              float* __restrict__ part) {
    __shared__ float4 sc4[CHUNK_SZ * 2];      // 5 KB: [node][2] float4 (GSUB=8)
    __shared__ float sdeg[CHUNK_SZ];
    __shared__ int   sbatch[CHUNK_SZ];
    __shared__ float4 red[2 * GSUB * 64];     // 16 KB cross-phase reduce

    const int t = threadIdx.x;
    const int fg = t & 63;                    // float4 feature group
    const int p  = t >> 6;                    // phase == wave id
    const int b = blockIdx.x & 127;           // same chunk's 8 splits: same XCD mod 8
    const int j = blockIdx.x >> 7;
    const int n0 = b * CHUNK_SZ;
    const int cnt = (n0 + CHUNK_SZ <= N_NODES) ? CHUNK_SZ : (N_NODES - n0);

    const float4* slab4 = (const float4*)(Cd + ((size_t)j * N_NODES + n0) * GSUB);
    for (int i = t; i < cnt * 2; i += 256) sc4[i] = slab4[i];
    if (j == 0) {
        for (int i = t; i < cnt; i += 256) {
            sdeg[i] = deg[n0 + i];
            sbatch[i] = batch[n0 + i];
        }
    }
    __syncthreads();

    const float4* x4 = (const float4*)x;
    float4 acc[GSUB];
#pragma unroll
    for (int k = 0; k < GSUB; ++k) acc[k] = make_float4(0.f, 0.f, 0.f, 0.f);

    if (j == 0) {
        float4 accs = make_float4(0.f, 0.f, 0.f, 0.f);
        int gprev = (p < cnt) ? sbatch[p] : 0;
        int i = p;
        float4 xn = make_float4(0.f, 0.f, 0.f, 0.f);
        if (i < cnt) xn = x4[(size_t)(n0 + i) * 64 + fg];
        for (; i < cnt; i += 4) {
            float4 xv = xn;
            if (i + 4 < cnt) xn = x4[(size_t)(n0 + i + 4) * 64 + fg];
            int g = sbatch[i];                  // wave-uniform
            if (g != gprev) {                   // uniform branch
                float* yr = Y + gprev * 256 + fg * 4;
                atomicAdd(yr + 0, accs.x); atomicAdd(yr + 1, accs.y);
                atomicAdd(yr + 2, accs.z); atomicAdd(yr + 3, accs.w);
                accs = make_float4(0.f, 0.f, 0.f, 0.f);
                gprev = g;
            }
            float dg = sdeg[i];
            accs.x = fmaf(dg, xv.x, accs.x); accs.y = fmaf(dg, xv.y, accs.y);
            accs.z = fmaf(dg, xv.z, accs.z); accs.w = fmaf(dg, xv.w, accs.w);
            float4 c0 = sc4[i * 2], c1 = sc4[i * 2 + 1];
            FMA8(c0, c1, xv)
        }
        if (p < cnt) {
            float* yr = Y + gprev * 256 + fg * 4;
            atomicAdd(yr + 0, accs.x); atomicAdd(yr + 1, accs.y);
            atomicAdd(yr + 2, accs.z); atomicAdd(yr + 3, accs.w);
        }
    } else {
        int i = p;
        float4 xn = make_float4(0.f, 0.f, 0.f, 0.f);
        if (i < cnt) xn = x4[(size_t)(n0 + i) * 64 + fg];
        for (; i < cnt; i += 4) {
            float4 xv = xn;
            if (i + 4 < cnt) xn = x4[(size_t)(n0 + i + 4) * 64 + fg];
            float4 c0 = sc4[i * 2], c1 = sc4[i * 2 + 1];
            FMA8(c0, c1, xv)
        }
    }

    // cross-phase reduce 4 -> 2 -> 1 (lane-consecutive, conflict-free)
    if (p >= 2) {
#pragma unroll
        for (int k = 0; k < GSUB; ++k) red[(p - 2) * (GSUB * 64) + k * 64 + fg] = acc[k];
    }
    __syncthreads();
    if (p < 2) {
#pragma unroll
        for (int k = 0; k < GSUB; ++k) {
            float4 v = red[p * (GSUB * 64) + k * 64 + fg];
            acc[k].x += v.x; acc[k].y += v.y; acc[k].z += v.z; acc[k].w += v.w;
        }
    }
    __syncthreads();
    if (p == 1) {
#pragma unroll
        for (int k = 0; k < GSUB; ++k) red[k * 64 + fg] = acc[k];
    }
    __syncthreads();
    if (p == 0) {
        float4* part4 = (float4*)part;
#pragma unroll
        for (int k = 0; k < GSUB; ++k) {
            float4 v = red[k * 64 + fg];
            acc[k].x += v.x; acc[k].y += v.y; acc[k].z += v.z; acc[k].w += v.w;
            part4[(size_t)(b * 64 + j * GSUB + k) * 64 + fg] = acc[k];
        }
    }
}

__global__ __launch_bounds__(256) void reduce_k(const float* __restrict__ part,
                                                float* __restrict__ Y) {
    __shared__ float4 red[3 * 64];
    const int j = blockIdx.x;           // dst graph 0..63
    const int l = threadIdx.x & 63;
    const int h = threadIdx.x >> 6;     // depth quarter
    const float4* part4 = (const float4*)part;
    float4 s = make_float4(0.f, 0.f, 0.f, 0.f);
    for (int bb = h * 32; bb < h * 32 + 32; ++bb) {
        float4 v = part4[(size_t)(bb * 64 + j) * 64 + l];
        s.x += v.x; s.y += v.y; s.z += v.z; s.w += v.w;
    }
    if (h > 0) red[(h - 1) * 64 + l] = s;
    __syncthreads();
    if (h == 0) {
#pragma unroll
        for (int q = 0; q < 3; ++q) {
            float4 v = red[q * 64 + l];
            s.x += v.x; s.y += v.y; s.z += v.z; s.w += v.w;
        }
        ((float4*)(Y + (64 + j) * 256))[l] = s;
    }
}

__global__ __launch_bounds__(128) void chain_k(const float* __restrict__ Y,
                                               const float* __restrict__ counts,
                                               const float* __restrict__ W0, const float* __restrict__ b0,
                                               const float* __restrict__ W1, const float* __restrict__ b1,
                                               const float* __restrict__ W2, const float* __restrict__ b2,
                                               float* __restrict__ out) {
    __shared__ float m[256];
    __shared__ float h[128];
    const int r = blockIdx.x;
    const int f = threadIdx.x;
    const int g = r & 63;
    const int half = (r >= 64) ? 128 : 0;

    float c = counts[g];
    float inv = 1.0f / fmaxf(c, 1.0f);
    float beta = c * inv;

    m[f]       = Y[r * 256 + f]       * inv;
    m[f + 128] = Y[r * 256 + f + 128] * inv;
    __syncthreads();

    float s1 = 0.0f;
    for (int k = 0; k < 256; ++k) s1 += m[k] * W0[k * 128 + f];
    s1 += beta * b0[f];
    out[g * 768 + 0 + half + f] = s1;
    h[f] = s1;
    __syncthreads();

    float s2 = 0.0f;
    for (int k = 0; k < 128; ++k) s2 += h[k] * W1[k * 128 + f];
    s2 += beta * b1[f];
    out[g * 768 + 256 + half + f] = s2;
    __syncthreads();
    h[f] = s2;
    __syncthreads();

    float s3 = 0.0f;
    for (int k = 0; k < 128; ++k) s3 += h[k] * W2[k * 128 + f];
    s3 += beta * b2[f];
    out[g * 768 + 512 + half + f] = s3;
}

extern "C" void kernel_launch(void* const* d_in, const int* in_sizes, int n_in,
                              void* d_out, int out_size, void* d_ws, size_t ws_size,
                              hipStream_t stream) {
    const float* x     = (const float*)d_in[0];
    const int*   ei    = (const int*)d_in[1];
    const int*   batch = (const int*)d_in[2];
    const float* W0    = (const float*)d_in[3];
    const float* b0    = (const float*)d_in[4];
    const float* W1    = (const float*)d_in[5];
    const float* b1    = (const float*)d_in[6];
    const float* W2    = (const float*)d_in[7];
    const float* b2    = (const float*)d_in[8];
    float* out = (float*)d_out;

    float*    ws      = (float*)d_ws;
    float*    Cd      = ws + CD_OFF;
    float*    deg     = ws + DEG_OFF;
    float*    counts  = ws + CNT_OFF;
    float*    Y       = ws + Y_OFF;
    float*    part    = ws + PART_OFF;
    unsigned* cdpart  = (unsigned*)(ws + CDPART_OFF);
    unsigned* degpart = (unsigned*)(ws + DEGPART_OFF);

    hist_k<<<NRANGE * NSLICE, 256, 0, stream>>>(ei, batch, cdpart, degpart, Y, counts);
    cd_reduce_k<<<N_NODES / 16, 256, 0, stream>>>(cdpart, degpart, batch, Cd, deg, counts);
    pool_k<<<NCHUNK * GSPLIT, 256, 0, stream>>>(x, batch, Cd, deg, Y, part);
    reduce_k<<<64, 256, 0, stream>>>(part, Y);
    chain_k<<<128, 128, 0, stream>>>(Y, counts, W0, b0, W1, b1, W2, b2, out);
}

// Round 6
// 140.176 us; speedup vs baseline: 1.4509x; 1.4509x over previous
//
#include <hip/hip_runtime.h>

#define N_NODES 20000
#define N_EDGES 640000
#define N_GRAPHS 64

// pool tiling
#define NCHUNK 128
#define CHUNK_SZ 157   // 128*157 = 20096 >= 20000
#define GSPLIT 8       // graph-dim split: 8 blocks of 8 graphs each
#define GSUB 8

// graph-bucket sort
#define GCAP 12288     // edges per graph: mean 10000, sigma ~99 -> 23 sigma margin
#define BG_TILE 2048
#define NBG 313        // ceil(640000/2048)

// ws layout (4B units), ws_size = 256 MiB:
//   Cdcol  [64][20000] f32     at 0          (1,280,000) column-major (per-graph column)
//   deg    [20000] f32         at 1,280,000  (zeroed by bucket_g_k blk0; sparse-written by cd_col_k)
//   counts [64] f32            at 1,300,000  (written dense by cd_col_k)
//   cursor [64] u32            at 1,300,064  (memset)
//   Y      [128][256] f32      at 1,300,128  (rows 0..63 zeroed by bucket_g_k blk0)
//   part   [128][64][256] f32  at 1,332,896  (2,097,152)
//   pairs  [64][12288] u64     at 3,430,048  (1,572,864 words; byte off 13,720,192 % 8 == 0)
// end = 5,002,912 words = 20 MB << 256 MiB
#define CD_OFF      0
#define DEG_OFF     1280000
#define CNT_OFF     1300000
#define CUR_OFF     1300064
#define Y_OFF       1300128
#define PART_OFF    1332896
#define PAIRS_OFF   3430048

// bucket edges by g = batch[src] (64 buckets). LDS rank + one cursor reservation
// per (block,g); pairs written in ~256B runs. Block 0 zeroes Y rows 0..63 and deg.
__global__ __launch_bounds__(256) void bucket_g_k(const int* __restrict__ ei,
                                                  const int* __restrict__ batch,
                                                  unsigned long long* __restrict__ pairs,
                                                  unsigned* __restrict__ cursor,
                                                  float* __restrict__ Y,
                                                  float* __restrict__ deg) {
    __shared__ unsigned hist[N_GRAPHS];
    __shared__ unsigned gbase[N_GRAPHS];
    const int t = threadIdx.x;
    if (t < N_GRAPHS) hist[t] = 0u;
    __syncthreads();

    const int e0 = blockIdx.x * BG_TILE;
    int sv[8], dv[8];
    unsigned rnk[8], gg[8];
#pragma unroll
    for (int k = 0; k < 8; ++k) {
        int e = e0 + t + k * 256;
        if (e < N_EDGES) {
            int s = ei[e];
            int d = ei[N_EDGES + e];
            int g = batch[s];
            sv[k] = s; dv[k] = d; gg[k] = (unsigned)g;
            rnk[k] = atomicAdd(&hist[g], 1u);
        } else {
            gg[k] = 0xFFFFFFFFu;
        }
    }
    __syncthreads();
    if (t < N_GRAPHS) {
        unsigned c = hist[t];
        gbase[t] = c ? atomicAdd(&cursor[t], c) : 0u;
    }
    __syncthreads();
#pragma unroll
    for (int k = 0; k < 8; ++k) {
        unsigned g = gg[k];
        if (g != 0xFFFFFFFFu) {
            unsigned slot = gbase[g] + rnk[k];
            if (slot < GCAP)
                pairs[(size_t)g * GCAP + slot] =
                    ((unsigned long long)(unsigned)sv[k] << 32) | (unsigned)dv[k];
        }
    }
    if (blockIdx.x == 0) {   // zero atomic/sparse targets (replaces big memset)
        float4* y4 = (float4*)Y;
        for (int i = t; i < 64 * 64; i += 256) y4[i] = make_float4(0.f, 0.f, 0.f, 0.f);
        float4* d4 = (float4*)deg;
        for (int i = t; i < N_NODES / 4; i += 256) d4[i] = make_float4(0.f, 0.f, 0.f, 0.f);
    }
}

// one block per graph g (1024 threads, 16 waves): replay bucket g, build full
// Cd column (dst-hist) + deg for g's node range (src-hist) in packed-u16 LDS.
__global__ __launch_bounds__(1024) void cd_col_k(const unsigned long long* __restrict__ pairs,
                                                 const unsigned* __restrict__ cursor,
                                                 float* __restrict__ Cdcol,
                                                 float* __restrict__ deg,
                                                 float* __restrict__ counts) {
    __shared__ unsigned dh[N_NODES / 2];    // 40 KB: dst counts, u16 halves
    __shared__ unsigned sh2[N_NODES / 2];   // 40 KB: src counts, u16 halves
    const int t = threadIdx.x;
    const int g = blockIdx.x;
    for (int i = t; i < N_NODES / 2; i += 1024) { dh[i] = 0u; sh2[i] = 0u; }
    __syncthreads();

    unsigned cnt = cursor[g];
    if (cnt > GCAP) cnt = GCAP;
    const unsigned long long* pv = pairs + (size_t)g * GCAP;
    for (unsigned i = t; i < cnt; i += 1024) {
        unsigned long long p = pv[i];
        unsigned s = (unsigned)(p >> 32);
        unsigned d = (unsigned)p;
        atomicAdd(&dh[d >> 1], 1u << ((d & 1u) * 16));
        atomicAdd(&sh2[s >> 1], 1u << ((s & 1u) * 16));
    }
    __syncthreads();

    float2* outc = (float2*)(Cdcol + (size_t)g * N_NODES);
    for (int w = t; w < N_NODES / 2; w += 1024) {
        unsigned v = dh[w];
        outc[w] = make_float2((float)(v & 0xFFFFu), (float)(v >> 16));
        unsigned u = sh2[w];
        if (u & 0xFFFFu) deg[2 * w]     = (float)(u & 0xFFFFu);   // srcs partition by
        if (u >> 16)     deg[2 * w + 1] = (float)(u >> 16);       // graph: no overlap
    }
    if (t == 0) counts[g] = (float)cnt;
}

#define FMA8(C0, C1, XV)                                          \
    acc[0].x = fmaf(C0.x, XV.x, acc[0].x); acc[0].y = fmaf(C0.x, XV.y, acc[0].y); \
    acc[0].z = fmaf(C0.x, XV.z, acc[0].z); acc[0].w = fmaf(C0.x, XV.w, acc[0].w); \
    acc[1].x = fmaf(C0.y, XV.x, acc[1].x); acc[1].y = fmaf(C0.y, XV.y, acc[1].y); \
    acc[1].z = fmaf(C0.y, XV.z, acc[1].z); acc[1].w = fmaf(C0.y, XV.w, acc[1].w); \
    acc[2].x = fmaf(C0.z, XV.x, acc[2].x); acc[2].y = fmaf(C0.z, XV.y, acc[2].y); \
    acc[2].z = fmaf(C0.z, XV.z, acc[2].z); acc[2].w = fmaf(C0.z, XV.w, acc[2].w); \
    acc[3].x = fmaf(C0.w, XV.x, acc[3].x); acc[3].y = fmaf(C0.w, XV.y, acc[3].y); \
    acc[3].z = fmaf(C0.w, XV.z, acc[3].z); acc[3].w = fmaf(C0.w, XV.w, acc[3].w); \
    acc[4].x = fmaf(C1.x, XV.x, acc[4].x); acc[4].y = fmaf(C1.x, XV.y, acc[4].y); \
    acc[4].z = fmaf(C1.x, XV.z, acc[4].z); acc[4].w = fmaf(C1.x, XV.w, acc[4].w); \
    acc[5].x = fmaf(C1.y, XV.x, acc[5].x); acc[5].y = fmaf(C1.y, XV.y, acc[5].y); \
    acc[5].z = fmaf(C1.y, XV.z, acc[5].z); acc[5].w = fmaf(C1.y, XV.w, acc[5].w); \
    acc[6].x = fmaf(C1.z, XV.x, acc[6].x); acc[6].y = fmaf(C1.z, XV.y, acc[6].y); \
    acc[6].z = fmaf(C1.z, XV.z, acc[6].z); acc[6].w = fmaf(C1.z, XV.w, acc[6].w); \
    acc[7].x = fmaf(C1.w, XV.x, acc[7].x); acc[7].y = fmaf(C1.w, XV.y, acc[7].y); \
    acc[7].z = fmaf(C1.w, XV.z, acc[7].z); acc[7].w = fmaf(C1.w, XV.w, acc[7].w);

// pool: block = (chunk b, split j of 8 graphs). 4 waves = 4 node phases,
// x prefetched one iteration ahead, Cd columns transposed into LDS, tree reduce.
__global__ __launch_bounds__(256) void pool_k(const float* __restrict__ x,
                                              const int* __restrict__ batch,
                                              const float* __restrict__ Cdcol,
                                              const float* __restrict__ deg,
                                              float* __restrict__ Y,
                                              float* __restrict__ part) {
    __shared__ float4 sc4[CHUNK_SZ * 2];      // 5 KB: [node][2] float4 (GSUB=8)
    __shared__ float sdeg[CHUNK_SZ];
    __shared__ int   sbatch[CHUNK_SZ];
    __shared__ float4 red[2 * GSUB * 64];     // 16 KB cross-phase reduce

    const int t = threadIdx.x;
    const int fg = t & 63;                    // float4 feature group
    const int p  = t >> 6;                    // phase == wave id
    const int b = blockIdx.x & 127;           // same chunk's 8 splits: same XCD mod 8
    const int j = blockIdx.x >> 7;
    const int n0 = b * CHUNK_SZ;
    const int cnt = (n0 + CHUNK_SZ <= N_NODES) ? CHUNK_SZ : (N_NODES - n0);

    // transpose-stage 8 Cd columns into [node][8] LDS layout
    float* sc = (float*)sc4;
    const float* cbase = Cdcol + (size_t)(j * GSUB) * N_NODES + n0;
#pragma unroll
    for (int k = 0; k < GSUB; ++k)
        for (int i = t; i < cnt; i += 256)
            sc[i * GSUB + k] = cbase[(size_t)k * N_NODES + i];
    if (j == 0) {
        for (int i = t; i < cnt; i += 256) {
            sdeg[i] = deg[n0 + i];
            sbatch[i] = batch[n0 + i];
        }
    }
    __syncthreads();

    const float4* x4 = (const float4*)x;
    float4 acc[GSUB];
#pragma unroll
    for (int k = 0; k < GSUB; ++k) acc[k] = make_float4(0.f, 0.f, 0.f, 0.f);

    if (j == 0) {
        float4 accs = make_float4(0.f, 0.f, 0.f, 0.f);
        int gprev = (p < cnt) ? sbatch[p] : 0;
        int i = p;
        float4 xn = make_float4(0.f, 0.f, 0.f, 0.f);
        if (i < cnt) xn = x4[(size_t)(n0 + i) * 64 + fg];
        for (; i < cnt; i += 4) {
            float4 xv = xn;
            if (i + 4 < cnt) xn = x4[(size_t)(n0 + i + 4) * 64 + fg];
            int g = sbatch[i];                  // wave-uniform
            if (g != gprev) {                   // uniform branch
                float* yr = Y + gprev * 256 + fg * 4;
                atomicAdd(yr + 0, accs.x); atomicAdd(yr + 1, accs.y);
                atomicAdd(yr + 2, accs.z); atomicAdd(yr + 3, accs.w);
                accs = make_float4(0.f, 0.f, 0.f, 0.f);
                gprev = g;
            }
            float dg = sdeg[i];
            accs.x = fmaf(dg, xv.x, accs.x); accs.y = fmaf(dg, xv.y, accs.y);
            accs.z = fmaf(dg, xv.z, accs.z); accs.w = fmaf(dg, xv.w, accs.w);
            float4 c0 = sc4[i * 2], c1 = sc4[i * 2 + 1];
            FMA8(c0, c1, xv)
        }
        if (p < cnt) {
            float* yr = Y + gprev * 256 + fg * 4;
            atomicAdd(yr + 0, accs.x); atomicAdd(yr + 1, accs.y);
            atomicAdd(yr + 2, accs.z); atomicAdd(yr + 3, accs.w);
        }
    } else {
        int i = p;
        float4 xn = make_float4(0.f, 0.f, 0.f, 0.f);
        if (i < cnt) xn = x4[(size_t)(n0 + i) * 64 + fg];
        for (; i < cnt; i += 4) {
            float4 xv = xn;
            if (i + 4 < cnt) xn = x4[(size_t)(n0 + i + 4) * 64 + fg];
            float4 c0 = sc4[i * 2], c1 = sc4[i * 2 + 1];
            FMA8(c0, c1, xv)
        }
    }

    // cross-phase reduce 4 -> 2 -> 1 (lane-consecutive, conflict-free)
    if (p >= 2) {
#pragma unroll
        for (int k = 0; k < GSUB; ++k) red[(p - 2) * (GSUB * 64) + k * 64 + fg] = acc[k];
    }
    __syncthreads();
    if (p < 2) {
#pragma unroll
        for (int k = 0; k < GSUB; ++k) {
            float4 v = red[p * (GSUB * 64) + k * 64 + fg];
            acc[k].x += v.x; acc[k].y += v.y; acc[k].z += v.z; acc[k].w += v.w;
        }
    }
    __syncthreads();
    if (p == 1) {
#pragma unroll
        for (int k = 0; k < GSUB; ++k) red[k * 64 + fg] = acc[k];
    }
    __syncthreads();
    if (p == 0) {
        float4* part4 = (float4*)part;
#pragma unroll
        for (int k = 0; k < GSUB; ++k) {
            float4 v = red[k * 64 + fg];
            acc[k].x += v.x; acc[k].y += v.y; acc[k].z += v.z; acc[k].w += v.w;
            part4[(size_t)(b * 64 + j * GSUB + k) * 64 + fg] = acc[k];
        }
    }
}

__global__ __launch_bounds__(256) void reduce_k(const float* __restrict__ part,
                                                float* __restrict__ Y) {
    __shared__ float4 red[3 * 64];
    const int j = blockIdx.x;           // dst graph 0..63
    const int l = threadIdx.x & 63;
    const int h = threadIdx.x >> 6;     // depth quarter
    const float4* part4 = (const float4*)part;
    float4 s = make_float4(0.f, 0.f, 0.f, 0.f);
    for (int bb = h * 32; bb < h * 32 + 32; ++bb) {
        float4 v = part4[(size_t)(bb * 64 + j) * 64 + l];
        s.x += v.x; s.y += v.y; s.z += v.z; s.w += v.w;
    }
    if (h > 0) red[(h - 1) * 64 + l] = s;
    __syncthreads();
    if (h == 0) {
#pragma unroll
        for (int q = 0; q < 3; ++q) {
            float4 v = red[q * 64 + l];
            s.x += v.x; s.y += v.y; s.z += v.z; s.w += v.w;
        }
        ((float4*)(Y + (64 + j) * 256))[l] = s;
    }
}

__global__ __launch_bounds__(128) void chain_k(const float* __restrict__ Y,
                                               const float* __restrict__ counts,
                                               const float* __restrict__ W0, const float* __restrict__ b0,
                                               const float* __restrict__ W1, const float* __restrict__ b1,
                                               const float* __restrict__ W2, const float* __restrict__ b2,
                                               float* __restrict__ out) {
    __shared__ float m[256];
    __shared__ float h[128];
    const int r = blockIdx.x;
    const int f = threadIdx.x;
    const int g = r & 63;
    const int half = (r >= 64) ? 128 : 0;

    float c = counts[g];
    float inv = 1.0f / fmaxf(c, 1.0f);
    float beta = c * inv;

    m[f]       = Y[r * 256 + f]       * inv;
    m[f + 128] = Y[r * 256 + f + 128] * inv;
    __syncthreads();

    float s1 = 0.0f;
    for (int k = 0; k < 256; ++k) s1 += m[k] * W0[k * 128 + f];
    s1 += beta * b0[f];
    out[g * 768 + 0 + half + f] = s1;
    h[f] = s1;
    __syncthreads();

    float s2 = 0.0f;
    for (int k = 0; k < 128; ++k) s2 += h[k] * W1[k * 128 + f];
    s2 += beta * b1[f];
    out[g * 768 + 256 + half + f] = s2;
    __syncthreads();
    h[f] = s2;
    __syncthreads();

    float s3 = 0.0f;
    for (int k = 0; k < 128; ++k) s3 += h[k] * W2[k * 128 + f];
    s3 += beta * b2[f];
    out[g * 768 + 512 + half + f] = s3;
}

extern "C" void kernel_launch(void* const* d_in, const int* in_sizes, int n_in,
                              void* d_out, int out_size, void* d_ws, size_t ws_size,
                              hipStream_t stream) {
    const float* x     = (const float*)d_in[0];
    const int*   ei    = (const int*)d_in[1];
    const int*   batch = (const int*)d_in[2];
    const float* W0    = (const float*)d_in[3];
    const float* b0    = (const float*)d_in[4];
    const float* W1    = (const float*)d_in[5];
    const float* b1    = (const float*)d_in[6];
    const float* W2    = (const float*)d_in[7];
    const float* b2    = (const float*)d_in[8];
    float* out = (float*)d_out;

    float*    ws     = (float*)d_ws;
    float*    Cdcol  = ws + CD_OFF;
    float*    deg    = ws + DEG_OFF;
    float*    counts = ws + CNT_OFF;
    unsigned* cursor = (unsigned*)(ws + CUR_OFF);
    float*    Y      = ws + Y_OFF;
    float*    part   = ws + PART_OFF;
    unsigned long long* pairs = (unsigned long long*)(ws + PAIRS_OFF);

    hipMemsetAsync(cursor, 0, N_GRAPHS * sizeof(unsigned), stream);
    bucket_g_k<<<NBG, 256, 0, stream>>>(ei, batch, pairs, cursor, Y, deg);
    cd_col_k<<<N_GRAPHS, 1024, 0, stream>>>(pairs, cursor, Cdcol, deg, counts);
    pool_k<<<NCHUNK * GSPLIT, 256, 0, stream>>>(x, batch, Cdcol, deg, Y, part);
    reduce_k<<<64, 256, 0, stream>>>(part, Y);
    chain_k<<<128, 128, 0, stream>>>(Y, counts, W0, b0, W1, b1, W2, b2, out);
}